// Round 21
// baseline (119.551 us; speedup 1.0000x reference)
//
#include <hip/hip_runtime.h>
#include <hip/hip_bf16.h>

#define H 160
#define W 160
#define HW 25600
#define ROWB 40960      // W * 256 bytes per NHWC row

typedef __attribute__((ext_vector_type(8))) short bf16x8;
typedef __attribute__((ext_vector_type(4))) float f32x4;
typedef __attribute__((ext_vector_type(8))) unsigned short ushort8v;
typedef __attribute__((ext_vector_type(4))) unsigned short ushort4v;

typedef __attribute__((address_space(1))) const unsigned int gu32;
typedef __attribute__((address_space(3))) unsigned int lu32;

__device__ __forceinline__ void gload16(const void* g, void* l) {
    __builtin_amdgcn_global_load_lds((gu32*)g, (lu32*)l, 16, 0, 0);
}

__device__ __forceinline__ unsigned short f2b(float f) {
    unsigned int u = __float_as_uint(f);
    unsigned int r = (u + 0x7fffu + ((u >> 16) & 1u)) >> 16;
    return (unsigned short)r;
}
__device__ __forceinline__ float b2f(unsigned short b) {
    return __uint_as_float(((unsigned int)b) << 16);
}

#define LGKM0() asm volatile("s_waitcnt lgkmcnt(0)" ::: "memory")
#define BARRIER() asm volatile("s_barrier" ::: "memory")

// ---------------------------------------------------------------------------
// Activation global format (16-B-slot swizzle, key = p&15):
//   pixel p: 256 B; slot for ci-block cb stored at slot cb^(p&15).
// Weight planes: [tap][kk] 8192 B planes of [co][64 B].
// d_out scratch (dead before conv4's head epilogue rewrites it):
//   [0,6553600) act X | [6553600,7733248) wbf layers 0-2 (+unused l3 slot) |
//   [7733248,7737344) BN inv/shift | [7737344,8516096) cwT (1152x169 f32)
// ws: [0,6553600) act Y | [6553600,6848512) layer-4 planes | [6848512,6849536)
//   layer-4 inv/shift | params at 7372800 (67,600 B)   (7,440,400 proven)
// conv4 reads ONLY ws -> its head-epilogue writes to d_out are race-free.
// ---------------------------------------------------------------------------

// ===========================================================================
// fused_prep (blockIdx ranges):
//   [0,200)    prep_in — 128 px/block, block-local full-slot coverage (proven)
//   [200,456)  prep_w  — layers 0-2 -> wbf (d_out); layer 3 -> ws copy
//   [456,1217) cw transpose: cwT[j*169+o] = cw[o*1152+j]  (coalesced writes)
// ===========================================================================
__global__ __launch_bounds__(256) void fused_prep(
    const float* __restrict__ cnn,
    const float* __restrict__ tw,
    const float* __restrict__ gamma, const float* __restrict__ beta,
    const float* __restrict__ mean,  const float* __restrict__ var,
    const float* __restrict__ cw,
    char* __restrict__ actX, char* __restrict__ wbf,
    float* __restrict__ invshift, float* __restrict__ cwT,
    char* __restrict__ wbf4, float* __restrict__ invshift4)
{
    const int tid = threadIdx.x;
    const int b = blockIdx.x;

    if (b < 200) {
        // ---------------- prep_in v4 (proven WRITE_SIZE-clean) -------------
        int blk = b;                            // 0..199
        int p0  = blk * 128 + (tid & 31) * 4;   // 4 consecutive pixels
        int cbh = tid >> 5;                     // 0..7
#pragma unroll
        for (int pass = 0; pass < 2; ++pass) {
            int cb2 = pass * 8 + cbh;
            int ci0 = cb2 * 8;
            ushort8v o0, o1, o2, o3;
#pragma unroll
            for (int jj = 0; jj < 8; ++jj) {
                float4 v = *(const float4*)&cnn[(ci0 + jj) * HW + p0];
                o0[jj] = f2b(v.x);
                o1[jj] = f2b(v.y);
                o2[jj] = f2b(v.z);
                o3[jj] = f2b(v.w);
            }
            *(ushort8v*)(actX + (p0 + 0) * 256 + ((cb2 ^ ((p0 + 0) & 15)) * 16)) = o0;
            *(ushort8v*)(actX + (p0 + 1) * 256 + ((cb2 ^ ((p0 + 1) & 15)) * 16)) = o1;
            *(ushort8v*)(actX + (p0 + 2) * 256 + ((cb2 ^ ((p0 + 2) & 15)) * 16)) = o2;
            *(ushort8v*)(actX + (p0 + 3) * 256 + ((cb2 ^ ((p0 + 3) & 15)) * 16)) = o3;
        }
    } else if (b < 456) {
        // ---------------- prep_weights (layer 3 goes to ws) ----------------
        int idx = (b - 200) * 256 + tid;            // 65,536 exact
        int ci = idx & 127;
        int co = (idx >> 7) & 127;
        int l  = idx >> 14;                          // 0..3
        int kk = ci >> 5;
        int cw2 = ci & 31;
        const float* src = tw + ((l * 128 + co) * 128 + ci) * 9;
        char* base = (l < 3) ? (wbf + l * 294912) : wbf4;
        char* dst = base + kk * 8192 + co * 64 + cw2 * 2;
#pragma unroll
        for (int t = 0; t < 9; ++t)
            *(unsigned short*)(dst + t * 32768) = f2b(src[t]);

        if (b == 200) {
            for (int c = tid; c < 512; c += 256) {
                int ll = c >> 7, ch = c & 127;
                float inv = gamma[ll * 128 + ch] * rsqrtf(var[ll * 128 + ch] + 1e-5f);
                float sh  = beta[ll * 128 + ch] - mean[ll * 128 + ch] * inv;
                invshift[ll * 256 + ch] = inv;
                invshift[ll * 256 + 128 + ch] = sh;
                if (ll == 3) {
                    invshift4[ch] = inv;
                    invshift4[128 + ch] = sh;
                }
            }
        }
    } else {
        // ---------------- cw transpose -------------------------------------
        int idx = (b - 456) * 256 + tid;            // < 194,688
        if (idx < 194688) {
            int j = idx / 169;
            int o = idx - j * 169;
            cwT[idx] = cw[o * 1152 + j];
        }
    }
}

// ===========================================================================
// conv_mfma v8 + fused ctrl v6 (CTRL=1) + fused proj+head (PROJ=1).
// Conv: 512 thr / 8 waves, tile 128co x 128px, 1-D grid b -> (b%10,b/10);
// 36-stage pipelined weight staging (validated R15-R20).
// PROJ=1: proj -> pmf in LDS, then the 3-layer head MLP for all 100
// detections over the block's 128 pixels (params in 5 LDS chunks of 20 k).
// ===========================================================================
template <int PROJ, int CTRL>
__global__ __launch_bounds__(512, 1) void conv_mfma(
    const char* __restrict__ actin,
    const char* __restrict__ wpl,         // 36 x 8192 B (this layer)
    const float* __restrict__ invshift_l, // 256 f32
    char* __restrict__ actout,            // PROJ=0
    const float* __restrict__ pw,         // PROJ=1: (8,128)
    const float* __restrict__ pb,         // (8)
    const float* __restrict__ cnn,        // CTRL=1
    const float* __restrict__ cwT,        // (1152,169)
    const float* __restrict__ cbp,        // (169)
    const int*   __restrict__ det,        // (100,2)
    float* __restrict__ params,           // (100,169)
    float* __restrict__ outp)             // PROJ=1: (100,160,160)
{
    __shared__ __align__(16) char smem[78848];

    const int tid  = threadIdx.x;

    if (CTRL && blockIdx.x >= 200) {
        // ---------------- ctrl v6: 3 K-chunks x 169 outputs (proven) -------
        float* patch = (float*)smem;            // 1152 f32
        float* sred  = (float*)(smem + 4608);   // 338 f32
        const int k = blockIdx.x - 200;
        const int xk = det[2 * k];
        const int yk = det[2 * k + 1];
        for (int i = tid; i < 1152; i += 512) {
            int ci = i / 9;
            int rem = i - ci * 9;
            int r = rem / 3, s = rem - r * 3;
            int gy = yk + r - 1, gx = xk + s - 1;
            float v = 0.f;
            if ((unsigned)gy < (unsigned)H && (unsigned)gx < (unsigned)W)
                v = cnn[ci * HW + gy * W + gx];
            patch[i] = v;
        }
        __syncthreads();

        float acc = 0.f;
        if (tid < 507) {
            const int chunk = tid / 169;        // 0..2
            const int o = tid - chunk * 169;
            const int j0 = chunk * 384;
            const float* cp = cwT + o;
#pragma unroll 8
            for (int j = j0; j < j0 + 384; ++j)
                acc += cp[j * 169] * patch[j];
        }
        if (tid >= 169 && tid < 507) sred[tid - 169] = acc;
        __syncthreads();
        if (tid < 169)
            params[k * 169 + tid] = acc + sred[tid] + sred[169 + tid] + cbp[tid];
        return;
    }

    char* IT = smem;                 // 46080 B : [10 rows][18 px][256 B]
    char* WQ = smem + 46080;         // 4 x 8192 B quarter-buffers

    const int lane = tid & 63;
    const int w    = tid >> 6;       // 0..7
    const int wp   = w >> 1;         // 0..3 : rows wp*2, wp*2+1
    const int wc   = w & 1;          // co half (64 co)
    const int g    = lane >> 4;
    const int i15  = lane & 15;

    const int bb = blockIdx.x;
    const int bx = bb % 10;          // 0..9
    const int by = bb / 10;          // 0..19
    const int tx0 = bx * 16 - 1;
    const int ty0 = by * 8 - 1;

    // ---- prologue: input tile DMA (clamped) + weight planes 0..2
    for (int it = 0; it < 6; ++it) {
        int c = it * 512 + tid;
        if (c < 2880) {                       // 2880 % 64 == 0: whole waves
            int row  = c / 288;
            int rem  = c - row * 288;
            int px_i = rem >> 4;
            int bo   = (rem & 15) * 16;
            int cy = min(max(ty0 + row, 0), H - 1);
            int cx = min(max(tx0 + px_i, 0), W - 1);
            char* ldsb = IT + (it * 512 + (tid & ~63)) * 16;
            gload16(actin + cy * ROWB + cx * 256 + bo, ldsb);
        }
    }
#pragma unroll
    for (int pl = 0; pl < 3; ++pl)
        gload16(wpl + pl * 8192 + tid * 16,
                WQ + pl * 8192 + (tid & ~63) * 16);
    asm volatile("s_waitcnt vmcnt(2)" ::: "memory");   // IT + plane 0 landed
    for (int c = tid; c < 2880; c += 512) {            // zero own OOB chunks
        int row  = c / 288;
        int rem  = c - row * 288;
        int px_i = rem >> 4;
        int gy = ty0 + row, gx = tx0 + px_i;
        if ((unsigned)gy >= (unsigned)H || (unsigned)gx >= (unsigned)W) {
            f32x4 z = {0.f, 0.f, 0.f, 0.f};
            *(f32x4*)(IT + c * 16) = z;
        }
    }
    LGKM0();
    BARRIER();

    f32x4 acc[4][2];                 // [cf][pf] — compile-time indices only
#pragma unroll
    for (int cf = 0; cf < 4; ++cf)
#pragma unroll
        for (int pf = 0; pf < 2; ++pf)
            acc[cf][pf] = (f32x4){0.f, 0.f, 0.f, 0.f};

#define CSTAGE(J, WN) {                                                        \
    if ((J) <= 32)                                                             \
        gload16(wpl + ((J) + 3) * 8192 + tid * 16,                             \
                WQ + (((J) + 3) & 3) * 8192 + (tid & ~63) * 16);               \
    asm volatile("s_waitcnt vmcnt(" #WN ")" ::: "memory");                     \
    {                                                                          \
        const int tap = (J) >> 2, kk = (J) & 3;                                \
        const int r = tap / 3, s = tap - r * 3;                                \
        const char* wbse = WQ + ((J) & 3) * 8192 + (wc * 64 + i15) * 64 + g * 16; \
        bf16x8 a0 = *(const bf16x8*)(wbse + 0 * 1024);                         \
        bf16x8 a1 = *(const bf16x8*)(wbse + 1 * 1024);                         \
        bf16x8 a2 = *(const bf16x8*)(wbse + 2 * 1024);                         \
        bf16x8 a3 = *(const bf16x8*)(wbse + 3 * 1024);                         \
        const int slotb = ((kk * 4 + g) ^ ((i15 + s + 15) & 15)) * 16;         \
        const char* ib = IT + (i15 + s) * 256 + slotb;                         \
        bf16x8 b0 = *(const bf16x8*)(ib + (wp * 2 + 0 + r) * 4608);            \
        bf16x8 b1 = *(const bf16x8*)(ib + (wp * 2 + 1 + r) * 4608);            \
        acc[0][0] = __builtin_amdgcn_mfma_f32_16x16x32_bf16(a0, b0, acc[0][0], 0, 0, 0); \
        acc[0][1] = __builtin_amdgcn_mfma_f32_16x16x32_bf16(a0, b1, acc[0][1], 0, 0, 0); \
        acc[1][0] = __builtin_amdgcn_mfma_f32_16x16x32_bf16(a1, b0, acc[1][0], 0, 0, 0); \
        acc[1][1] = __builtin_amdgcn_mfma_f32_16x16x32_bf16(a1, b1, acc[1][1], 0, 0, 0); \
        acc[2][0] = __builtin_amdgcn_mfma_f32_16x16x32_bf16(a2, b0, acc[2][0], 0, 0, 0); \
        acc[2][1] = __builtin_amdgcn_mfma_f32_16x16x32_bf16(a2, b1, acc[2][1], 0, 0, 0); \
        acc[3][0] = __builtin_amdgcn_mfma_f32_16x16x32_bf16(a3, b0, acc[3][0], 0, 0, 0); \
        acc[3][1] = __builtin_amdgcn_mfma_f32_16x16x32_bf16(a3, b1, acc[3][1], 0, 0, 0); \
    }                                                                          \
    BARRIER();                                                                 \
}

    CSTAGE(0,2)  CSTAGE(1,2)  CSTAGE(2,2)  CSTAGE(3,2)  CSTAGE(4,2)  CSTAGE(5,2)
    CSTAGE(6,2)  CSTAGE(7,2)  CSTAGE(8,2)  CSTAGE(9,2)  CSTAGE(10,2) CSTAGE(11,2)
    CSTAGE(12,2) CSTAGE(13,2) CSTAGE(14,2) CSTAGE(15,2) CSTAGE(16,2) CSTAGE(17,2)
    CSTAGE(18,2) CSTAGE(19,2) CSTAGE(20,2) CSTAGE(21,2) CSTAGE(22,2) CSTAGE(23,2)
    CSTAGE(24,2) CSTAGE(25,2) CSTAGE(26,2) CSTAGE(27,2) CSTAGE(28,2) CSTAGE(29,2)
    CSTAGE(30,2) CSTAGE(31,2) CSTAGE(32,2) CSTAGE(33,1) CSTAGE(34,0) CSTAGE(35,0)
#undef CSTAGE

    // ---- epilogue ---------------------------------------------------------
    if (PROJ == 0) {
        const int gx = bx * 16 + i15;    // gx & 15 == i15
#pragma unroll
        for (int cf = 0; cf < 4; ++cf) {
            int co0 = wc * 64 + cf * 16 + g * 4;
            int cbx = wc * 8 + cf * 2 + (g >> 1);
            int sbyte = ((cbx ^ i15) * 16) + (g & 1) * 8;
            f32x4 inv4 = *(const f32x4*)&invshift_l[co0];
            f32x4 sh4  = *(const f32x4*)&invshift_l[128 + co0];
#pragma unroll
            for (int pf = 0; pf < 2; ++pf) {
                int gy = by * 8 + wp * 2 + pf;
                f32x4 v = acc[cf][pf];
                ushort4v o;
                o.x = f2b(fmaxf(v.x * inv4.x + sh4.x, 0.f));
                o.y = f2b(fmaxf(v.y * inv4.y + sh4.y, 0.f));
                o.z = f2b(fmaxf(v.z * inv4.z + sh4.z, 0.f));
                o.w = f2b(fmaxf(v.w * inv4.w + sh4.w, 0.f));
                *(ushort4v*)(actout + gy * ROWB + gx * 256 + sbyte) = o;
            }
        }
    } else {
        // ---- fused projection + head MLP ----------------------------------
        char* actF  = smem;                      // 32 KB [128px][256B]
        float* spw  = (float*)(smem + 32768);    // 1024 f32
        float* pmf  = (float*)(smem + 36864);    // 128 x 8 f32
        float* spar = (float*)(smem + 40960);    // 20 x 169 f32 (13520 B)
        int*   sdet = (int*)(smem + 54480);      // 200 ints
        __syncthreads();                         // everyone done with IT/WQ
#pragma unroll
        for (int cf = 0; cf < 4; ++cf) {
            int co0 = wc * 64 + cf * 16 + g * 4;
            int cbx = wc * 8 + cf * 2 + (g >> 1);
            int sbyte = ((cbx ^ i15) * 16) + (g & 1) * 8;
            f32x4 inv4 = *(const f32x4*)&invshift_l[co0];
            f32x4 sh4  = *(const f32x4*)&invshift_l[128 + co0];
#pragma unroll
            for (int pf = 0; pf < 2; ++pf) {
                int px = (wp * 2 + pf) * 16 + i15;   // px & 15 == i15
                f32x4 v = acc[cf][pf];
                ushort4v o;
                o.x = f2b(fmaxf(v.x * inv4.x + sh4.x, 0.f));
                o.y = f2b(fmaxf(v.y * inv4.y + sh4.y, 0.f));
                o.z = f2b(fmaxf(v.z * inv4.z + sh4.z, 0.f));
                o.w = f2b(fmaxf(v.w * inv4.w + sh4.w, 0.f));
                *(ushort4v*)(actF + px * 256 + sbyte) = o;
            }
        }
        for (int i = tid; i < 1024; i += 512) spw[i] = pw[i];
        for (int i = tid; i < 200; i += 512) sdet[i] = det[i];
        __syncthreads();
        // projection for this thread's (pixel, channel-pair)
        {
            int pxt = tid >> 2;            // 0..127
            int o0  = (tid & 3) * 2;       // 0,2,4,6
            float s0 = 0.f, s1 = 0.f;
#pragma unroll
            for (int cb2 = 0; cb2 < 16; ++cb2) {
                ushort8v vv = *(const ushort8v*)(actF + pxt * 256 + ((cb2 ^ (pxt & 15)) * 16));
#pragma unroll
                for (int j = 0; j < 8; ++j) {
                    float fv = b2f(vv[j]);
                    int ci = cb2 * 8 + j;
                    s0 += fv * spw[o0 * 128 + ci];
                    s1 += fv * spw[(o0 + 1) * 128 + ci];
                }
            }
            pmf[pxt * 8 + o0]     = s0 + pb[o0];
            pmf[pxt * 8 + o0 + 1] = s1 + pb[o0 + 1];
        }
        __syncthreads();
        // head MLP: thread owns pixel px = tid>>2, handles k = (tid&3)+4j
        const int px  = tid >> 2;
        const int kq  = tid & 3;
        const int lx  = px & 15, ly = px >> 4;
        const int gpx = (by * 8 + ly) * W + bx * 16 + lx;
        const float fx = (float)((bx * 16 + lx) * 4 + 2);
        const float fy = (float)((by * 8 + ly) * 4 + 2);
        float f[8];
#pragma unroll
        for (int o = 0; o < 8; ++o) f[o] = pmf[px * 8 + o];

        for (int chunk = 0; chunk < 5; ++chunk) {
            for (int i = tid; i < 3380; i += 512)
                spar[i] = params[chunk * 3380 + i];
            __syncthreads();
#pragma unroll
            for (int jj = 0; jj < 5; ++jj) {
                int kl = kq + jj * 4;              // 0..19
                int k  = chunk * 20 + kl;
                const float* spj = &spar[kl * 169];
                float rel0 = (float)(sdet[2 * k] * 4) - fx;
                float rel1 = (float)(sdet[2 * k + 1] * 4) - fy;
                float h0[8];
#pragma unroll
                for (int o = 0; o < 8; ++o) {
                    float a = spj[152 + o] + spj[o * 10] * rel0 + spj[o * 10 + 1] * rel1;
#pragma unroll
                    for (int c = 0; c < 8; ++c) a += spj[o * 10 + 2 + c] * f[c];
                    h0[o] = fmaxf(a, 0.f);
                }
                float h1[8];
#pragma unroll
                for (int o = 0; o < 8; ++o) {
                    float a = spj[160 + o];
#pragma unroll
                    for (int c = 0; c < 8; ++c) a += spj[80 + o * 8 + c] * h0[c];
                    h1[o] = fmaxf(a, 0.f);
                }
                float r = spj[168];
#pragma unroll
                for (int c = 0; c < 8; ++c) r += spj[144 + c] * h1[c];
                outp[k * HW + gpx] = r;
            }
            __syncthreads();
        }
    }
}

// ===========================================================================
extern "C" void kernel_launch(void* const* d_in, const int* in_sizes, int n_in,
                              void* d_out, int out_size, void* d_ws, size_t ws_size,
                              hipStream_t stream)
{
    const float* cnn    = (const float*)d_in[0];
    const float* towerw = (const float*)d_in[1];
    const float* gamma  = (const float*)d_in[2];
    const float* beta   = (const float*)d_in[3];
    const float* meanp  = (const float*)d_in[4];
    const float* varp   = (const float*)d_in[5];
    const float* projw  = (const float*)d_in[6];
    const float* projb  = (const float*)d_in[7];
    const float* ctrlw  = (const float*)d_in[8];
    const float* ctrlb  = (const float*)d_in[9];
    const int*   det    = (const int*)d_in[10];
    float* out = (float*)d_out;

    char*  outb     = (char*)d_out;
    char*  X        = outb;                          // 6,553,600 B
    char*  wbf      = outb + 6553600;                // layers 0-2 planes
    float* invshift = (float*)(outb + 7733248);      // 4,096 B
    float* cwT      = (float*)(outb + 7737344);      // 778,752 B

    char*  Y         = (char*)d_ws;                      // 6,553,600 B
    char*  wbf4      = (char*)d_ws + 6553600;            // 294,912 B (layer 4)
    float* invshift4 = (float*)((char*)d_ws + 6848512);  // 1,024 B
    float* params    = (float*)((char*)d_ws + 7372800);  // 67,600 B

    fused_prep<<<dim3(1217), dim3(256), 0, stream>>>(
        cnn, towerw, gamma, beta, meanp, varp, ctrlw,
        X, wbf, invshift, cwT, wbf4, invshift4);

    // conv1 carries the 100 ctrl blocks (hidden under the conv's runtime)
    conv_mfma<0, 1><<<dim3(300), dim3(512), 0, stream>>>(
        X, wbf + 0 * 294912, invshift + 0 * 256, Y,
        nullptr, nullptr,
        cnn, cwT, ctrlb, det, params, nullptr);
    conv_mfma<0, 0><<<dim3(200), dim3(512), 0, stream>>>(
        Y, wbf + 1 * 294912, invshift + 1 * 256, X,
        nullptr, nullptr,
        nullptr, nullptr, nullptr, nullptr, nullptr, nullptr);
    conv_mfma<0, 0><<<dim3(200), dim3(512), 0, stream>>>(
        X, wbf + 2 * 294912, invshift + 2 * 256, Y,
        nullptr, nullptr,
        nullptr, nullptr, nullptr, nullptr, nullptr, nullptr);
    // conv4: reads ONLY ws (Y, wbf4, invshift4, params) -> head writes to
    // d_out are race-free; proj+head fused, no separate head dispatch.
    conv_mfma<1, 0><<<dim3(200), dim3(512), 0, stream>>>(
        Y, wbf4, invshift4, nullptr,
        projw, projb,
        nullptr, nullptr, nullptr, det, params, out);
}

// Round 22
// 103.981 us; speedup vs baseline: 1.1497x; 1.1497x over previous
//
#include <hip/hip_runtime.h>
#include <hip/hip_bf16.h>

#define H 160
#define W 160
#define HW 25600
#define ROWB 40960      // W * 256 bytes per NHWC row

typedef __attribute__((ext_vector_type(8))) short bf16x8;
typedef __attribute__((ext_vector_type(4))) float f32x4;
typedef __attribute__((ext_vector_type(8))) unsigned short ushort8v;
typedef __attribute__((ext_vector_type(4))) unsigned short ushort4v;

typedef __attribute__((address_space(1))) const unsigned int gu32;
typedef __attribute__((address_space(3))) unsigned int lu32;

__device__ __forceinline__ void gload16(const void* g, void* l) {
    __builtin_amdgcn_global_load_lds((gu32*)g, (lu32*)l, 16, 0, 0);
}

__device__ __forceinline__ unsigned short f2b(float f) {
    unsigned int u = __float_as_uint(f);
    unsigned int r = (u + 0x7fffu + ((u >> 16) & 1u)) >> 16;
    return (unsigned short)r;
}
__device__ __forceinline__ float b2f(unsigned short b) {
    return __uint_as_float(((unsigned int)b) << 16);
}

#define LGKM0() asm volatile("s_waitcnt lgkmcnt(0)" ::: "memory")
#define BARRIER() asm volatile("s_barrier" ::: "memory")

// ---------------------------------------------------------------------------
// Activation global format (16-B-slot swizzle, key = p&15):
//   pixel p: 256 B; slot for ci-block cb stored at slot cb^(p&15).
// Weight planes: [l][tap][kk] 8192 B planes of [co][64 B].
// d_out scratch: [0,6553600) act X | [6553600,7733248) wbf |
//   [7733248,7737344) BN inv/shift | [7737344,8516096) cwT (1152x169 f32)
// ws: [0,6553600) act Y | mf 819200 B | params 67600 B   (7,440,400 proven)
// ---------------------------------------------------------------------------

// ===========================================================================
// fused_prep (blockIdx ranges):
//   [0,200)    prep_in — 128 px/block, block-local full-slot coverage (proven)
//   [200,456)  prep_w  — proven coalesced weight transform + BN constants
//   [456,1217) cw transpose: cwT[j*169+o] = cw[o*1152+j]  (coalesced writes)
// ===========================================================================
__global__ __launch_bounds__(256) void fused_prep(
    const float* __restrict__ cnn,
    const float* __restrict__ tw,
    const float* __restrict__ gamma, const float* __restrict__ beta,
    const float* __restrict__ mean,  const float* __restrict__ var,
    const float* __restrict__ cw,
    char* __restrict__ actX, char* __restrict__ wbf,
    float* __restrict__ invshift, float* __restrict__ cwT)
{
    const int tid = threadIdx.x;
    const int b = blockIdx.x;

    if (b < 200) {
        // ---------------- prep_in v4 (proven WRITE_SIZE-clean) -------------
        int blk = b;                            // 0..199
        int p0  = blk * 128 + (tid & 31) * 4;   // 4 consecutive pixels
        int cbh = tid >> 5;                     // 0..7
#pragma unroll
        for (int pass = 0; pass < 2; ++pass) {
            int cb2 = pass * 8 + cbh;
            int ci0 = cb2 * 8;
            ushort8v o0, o1, o2, o3;
#pragma unroll
            for (int jj = 0; jj < 8; ++jj) {
                float4 v = *(const float4*)&cnn[(ci0 + jj) * HW + p0];
                o0[jj] = f2b(v.x);
                o1[jj] = f2b(v.y);
                o2[jj] = f2b(v.z);
                o3[jj] = f2b(v.w);
            }
            *(ushort8v*)(actX + (p0 + 0) * 256 + ((cb2 ^ ((p0 + 0) & 15)) * 16)) = o0;
            *(ushort8v*)(actX + (p0 + 1) * 256 + ((cb2 ^ ((p0 + 1) & 15)) * 16)) = o1;
            *(ushort8v*)(actX + (p0 + 2) * 256 + ((cb2 ^ ((p0 + 2) & 15)) * 16)) = o2;
            *(ushort8v*)(actX + (p0 + 3) * 256 + ((cb2 ^ ((p0 + 3) & 15)) * 16)) = o3;
        }
    } else if (b < 456) {
        // ---------------- prep_weights (proven) ----------------------------
        int idx = (b - 200) * 256 + tid;            // 65,536 exact
        int ci = idx & 127;
        int co = (idx >> 7) & 127;
        int l  = idx >> 14;                          // 0..3
        int kk = ci >> 5;
        int cw2 = ci & 31;
        const float* src = tw + ((l * 128 + co) * 128 + ci) * 9;
        char* dst = wbf + l * 294912 + kk * 8192 + co * 64 + cw2 * 2;
#pragma unroll
        for (int t = 0; t < 9; ++t)
            *(unsigned short*)(dst + t * 32768) = f2b(src[t]);

        if (b == 200) {
            for (int c = tid; c < 512; c += 256) {
                int ll = c >> 7, ch = c & 127;
                float inv = gamma[ll * 128 + ch] * rsqrtf(var[ll * 128 + ch] + 1e-5f);
                float sh  = beta[ll * 128 + ch] - mean[ll * 128 + ch] * inv;
                invshift[ll * 256 + ch] = inv;
                invshift[ll * 256 + 128 + ch] = sh;
            }
        }
    } else {
        // ---------------- cw transpose -------------------------------------
        int idx = (b - 456) * 256 + tid;            // < 194,688
        if (idx < 194688) {
            int j = idx / 169;
            int o = idx - j * 169;
            cwT[idx] = cw[o * 1152 + j];
        }
    }
}

// ===========================================================================
// conv_mfma v8 + fused ctrl v6 (CTRL=1: blocks >= 200).
// ctrl v6: 507 threads = 3 K-chunks x 169 outputs; per-thread 384-elem
// partial dot (coalesced cwT, LDS-broadcast patch), LDS-combined.
// Conv part: 512 thr / 8 waves, tile 128co x 128px, 1-D grid b -> (b%10,b/10);
// 36-stage pipelined weight staging (validated R15-R20).
// ===========================================================================
template <int PROJ, int CTRL>
__global__ __launch_bounds__(512, 1) void conv_mfma(
    const char* __restrict__ actin,
    const char* __restrict__ wpl,         // 36 x 8192 B (this layer)
    const float* __restrict__ invshift_l, // 256 f32
    char* __restrict__ actout,            // PROJ=0
    const float* __restrict__ pw,         // PROJ=1: (8,128)
    const float* __restrict__ pb,         // (8)
    float* __restrict__ mf,               // (8,HW)
    const float* __restrict__ cnn,        // CTRL=1
    const float* __restrict__ cwT,        // (1152,169)
    const float* __restrict__ cbp,        // (169)
    const int*   __restrict__ det,        // (100,2)
    float* __restrict__ params)           // (100,169)
{
    __shared__ __align__(16) char smem[78848];

    const int tid  = threadIdx.x;

    if (CTRL && blockIdx.x >= 200) {
        // ---------------- ctrl v6: 3 K-chunks x 169 outputs ---------------
        float* patch = (float*)smem;            // 1152 f32
        float* sred  = (float*)(smem + 4608);   // 338 f32
        const int k = blockIdx.x - 200;
        const int xk = det[2 * k];
        const int yk = det[2 * k + 1];
        for (int i = tid; i < 1152; i += 512) {
            int ci = i / 9;
            int rem = i - ci * 9;
            int r = rem / 3, s = rem - r * 3;
            int gy = yk + r - 1, gx = xk + s - 1;
            float v = 0.f;
            if ((unsigned)gy < (unsigned)H && (unsigned)gx < (unsigned)W)
                v = cnn[ci * HW + gy * W + gx];
            patch[i] = v;
        }
        __syncthreads();

        float acc = 0.f;
        if (tid < 507) {
            const int chunk = tid / 169;        // 0..2
            const int o = tid - chunk * 169;
            const int j0 = chunk * 384;
            const float* cp = cwT + o;
#pragma unroll 8
            for (int j = j0; j < j0 + 384; ++j)
                acc += cp[j * 169] * patch[j];
        }
        if (tid >= 169 && tid < 507) sred[tid - 169] = acc;
        __syncthreads();
        if (tid < 169)
            params[k * 169 + tid] = acc + sred[tid] + sred[169 + tid] + cbp[tid];
        return;
    }

    char* IT = smem;                 // 46080 B : [10 rows][18 px][256 B]
    char* WQ = smem + 46080;         // 4 x 8192 B quarter-buffers

    const int lane = tid & 63;
    const int w    = tid >> 6;       // 0..7
    const int wp   = w >> 1;         // 0..3 : rows wp*2, wp*2+1
    const int wc   = w & 1;          // co half (64 co)
    const int g    = lane >> 4;
    const int i15  = lane & 15;

    const int bb = blockIdx.x;
    const int bx = bb % 10;          // 0..9
    const int by = bb / 10;          // 0..19
    const int tx0 = bx * 16 - 1;
    const int ty0 = by * 8 - 1;

    // ---- prologue: input tile DMA (clamped) + weight planes 0..2
    for (int it = 0; it < 6; ++it) {
        int c = it * 512 + tid;
        if (c < 2880) {                       // 2880 % 64 == 0: whole waves
            int row  = c / 288;
            int rem  = c - row * 288;
            int px_i = rem >> 4;
            int bo   = (rem & 15) * 16;
            int cy = min(max(ty0 + row, 0), H - 1);
            int cx = min(max(tx0 + px_i, 0), W - 1);
            char* ldsb = IT + (it * 512 + (tid & ~63)) * 16;
            gload16(actin + cy * ROWB + cx * 256 + bo, ldsb);
        }
    }
#pragma unroll
    for (int pl = 0; pl < 3; ++pl)
        gload16(wpl + pl * 8192 + tid * 16,
                WQ + pl * 8192 + (tid & ~63) * 16);
    asm volatile("s_waitcnt vmcnt(2)" ::: "memory");   // IT + plane 0 landed
    for (int c = tid; c < 2880; c += 512) {            // zero own OOB chunks
        int row  = c / 288;
        int rem  = c - row * 288;
        int px_i = rem >> 4;
        int gy = ty0 + row, gx = tx0 + px_i;
        if ((unsigned)gy >= (unsigned)H || (unsigned)gx >= (unsigned)W) {
            f32x4 z = {0.f, 0.f, 0.f, 0.f};
            *(f32x4*)(IT + c * 16) = z;
        }
    }
    LGKM0();
    BARRIER();

    f32x4 acc[4][2];                 // [cf][pf] — compile-time indices only
#pragma unroll
    for (int cf = 0; cf < 4; ++cf)
#pragma unroll
        for (int pf = 0; pf < 2; ++pf)
            acc[cf][pf] = (f32x4){0.f, 0.f, 0.f, 0.f};

#define CSTAGE(J, WN) {                                                        \
    if ((J) <= 32)                                                             \
        gload16(wpl + ((J) + 3) * 8192 + tid * 16,                             \
                WQ + (((J) + 3) & 3) * 8192 + (tid & ~63) * 16);               \
    asm volatile("s_waitcnt vmcnt(" #WN ")" ::: "memory");                     \
    {                                                                          \
        const int tap = (J) >> 2, kk = (J) & 3;                                \
        const int r = tap / 3, s = tap - r * 3;                                \
        const char* wbse = WQ + ((J) & 3) * 8192 + (wc * 64 + i15) * 64 + g * 16; \
        bf16x8 a0 = *(const bf16x8*)(wbse + 0 * 1024);                         \
        bf16x8 a1 = *(const bf16x8*)(wbse + 1 * 1024);                         \
        bf16x8 a2 = *(const bf16x8*)(wbse + 2 * 1024);                         \
        bf16x8 a3 = *(const bf16x8*)(wbse + 3 * 1024);                         \
        const int slotb = ((kk * 4 + g) ^ ((i15 + s + 15) & 15)) * 16;         \
        const char* ib = IT + (i15 + s) * 256 + slotb;                         \
        bf16x8 b0 = *(const bf16x8*)(ib + (wp * 2 + 0 + r) * 4608);            \
        bf16x8 b1 = *(const bf16x8*)(ib + (wp * 2 + 1 + r) * 4608);            \
        acc[0][0] = __builtin_amdgcn_mfma_f32_16x16x32_bf16(a0, b0, acc[0][0], 0, 0, 0); \
        acc[0][1] = __builtin_amdgcn_mfma_f32_16x16x32_bf16(a0, b1, acc[0][1], 0, 0, 0); \
        acc[1][0] = __builtin_amdgcn_mfma_f32_16x16x32_bf16(a1, b0, acc[1][0], 0, 0, 0); \
        acc[1][1] = __builtin_amdgcn_mfma_f32_16x16x32_bf16(a1, b1, acc[1][1], 0, 0, 0); \
        acc[2][0] = __builtin_amdgcn_mfma_f32_16x16x32_bf16(a2, b0, acc[2][0], 0, 0, 0); \
        acc[2][1] = __builtin_amdgcn_mfma_f32_16x16x32_bf16(a2, b1, acc[2][1], 0, 0, 0); \
        acc[3][0] = __builtin_amdgcn_mfma_f32_16x16x32_bf16(a3, b0, acc[3][0], 0, 0, 0); \
        acc[3][1] = __builtin_amdgcn_mfma_f32_16x16x32_bf16(a3, b1, acc[3][1], 0, 0, 0); \
    }                                                                          \
    BARRIER();                                                                 \
}

    CSTAGE(0,2)  CSTAGE(1,2)  CSTAGE(2,2)  CSTAGE(3,2)  CSTAGE(4,2)  CSTAGE(5,2)
    CSTAGE(6,2)  CSTAGE(7,2)  CSTAGE(8,2)  CSTAGE(9,2)  CSTAGE(10,2) CSTAGE(11,2)
    CSTAGE(12,2) CSTAGE(13,2) CSTAGE(14,2) CSTAGE(15,2) CSTAGE(16,2) CSTAGE(17,2)
    CSTAGE(18,2) CSTAGE(19,2) CSTAGE(20,2) CSTAGE(21,2) CSTAGE(22,2) CSTAGE(23,2)
    CSTAGE(24,2) CSTAGE(25,2) CSTAGE(26,2) CSTAGE(27,2) CSTAGE(28,2) CSTAGE(29,2)
    CSTAGE(30,2) CSTAGE(31,2) CSTAGE(32,2) CSTAGE(33,1) CSTAGE(34,0) CSTAGE(35,0)
#undef CSTAGE

    // ---- epilogue ---------------------------------------------------------
    if (PROJ == 0) {
        const int gx = bx * 16 + i15;    // gx & 15 == i15
#pragma unroll
        for (int cf = 0; cf < 4; ++cf) {
            int co0 = wc * 64 + cf * 16 + g * 4;
            int cbx = wc * 8 + cf * 2 + (g >> 1);
            int sbyte = ((cbx ^ i15) * 16) + (g & 1) * 8;
            f32x4 inv4 = *(const f32x4*)&invshift_l[co0];
            f32x4 sh4  = *(const f32x4*)&invshift_l[128 + co0];
#pragma unroll
            for (int pf = 0; pf < 2; ++pf) {
                int gy = by * 8 + wp * 2 + pf;
                f32x4 v = acc[cf][pf];
                ushort4v o;
                o.x = f2b(fmaxf(v.x * inv4.x + sh4.x, 0.f));
                o.y = f2b(fmaxf(v.y * inv4.y + sh4.y, 0.f));
                o.z = f2b(fmaxf(v.z * inv4.z + sh4.z, 0.f));
                o.w = f2b(fmaxf(v.w * inv4.w + sh4.w, 0.f));
                *(ushort4v*)(actout + gy * ROWB + gx * 256 + sbyte) = o;
            }
        }
    } else {
        // fused projection: BN'd layer-4 acts -> actF in LDS, then 8-ch proj
        char* actF = smem;                       // 32 KB [128px][256B]
        float* spw = (float*)(smem + 32768);     // 4 KB
        __syncthreads();                         // everyone done with IT/WQ
#pragma unroll
        for (int cf = 0; cf < 4; ++cf) {
            int co0 = wc * 64 + cf * 16 + g * 4;
            int cbx = wc * 8 + cf * 2 + (g >> 1);
            int sbyte = ((cbx ^ i15) * 16) + (g & 1) * 8;
            f32x4 inv4 = *(const f32x4*)&invshift_l[co0];
            f32x4 sh4  = *(const f32x4*)&invshift_l[128 + co0];
#pragma unroll
            for (int pf = 0; pf < 2; ++pf) {
                int px = (wp * 2 + pf) * 16 + i15;   // px & 15 == i15
                f32x4 v = acc[cf][pf];
                ushort4v o;
                o.x = f2b(fmaxf(v.x * inv4.x + sh4.x, 0.f));
                o.y = f2b(fmaxf(v.y * inv4.y + sh4.y, 0.f));
                o.z = f2b(fmaxf(v.z * inv4.z + sh4.z, 0.f));
                o.w = f2b(fmaxf(v.w * inv4.w + sh4.w, 0.f));
                *(ushort4v*)(actF + px * 256 + sbyte) = o;
            }
        }
        for (int i = tid; i < 1024; i += 512) spw[i] = pw[i];
        __syncthreads();
        int pxt = tid >> 2;            // 0..127
        int o0  = (tid & 3) * 2;       // 0,2,4,6
        float s0 = 0.f, s1 = 0.f;
#pragma unroll
        for (int cb2 = 0; cb2 < 16; ++cb2) {
            ushort8v vv = *(const ushort8v*)(actF + pxt * 256 + ((cb2 ^ (pxt & 15)) * 16));
#pragma unroll
            for (int j = 0; j < 8; ++j) {
                float f = b2f(vv[j]);
                int ci = cb2 * 8 + j;
                s0 += f * spw[o0 * 128 + ci];
                s1 += f * spw[(o0 + 1) * 128 + ci];
            }
        }
        int p = (by * 8 + (pxt >> 4)) * W + bx * 16 + (pxt & 15);
        mf[o0 * HW + p]       = s0 + pb[o0];
        mf[(o0 + 1) * HW + p] = s1 + pb[o0 + 1];
    }
}

// ===========================================================================
// head: 10 detections per block; mf read once, reused 10x (proven).
// ===========================================================================
__global__ __launch_bounds__(256) void head_kernel(
    const float* __restrict__ mf, const float* __restrict__ params,
    const int* __restrict__ det, float* __restrict__ out)
{
    __shared__ float sp[1690];
    __shared__ int sdet[20];
    const int tid = threadIdx.x;
    const int kg = blockIdx.y;
    for (int i = tid; i < 1690; i += 256) sp[i] = params[kg * 1690 + i];
    if (tid < 20) sdet[tid] = det[kg * 20 + tid];
    __syncthreads();

    const int p = blockIdx.x * 256 + tid;
    const int x = p % W;
    const int y = p / W;
    const float fx = (float)(x * 4 + 2);
    const float fy = (float)(y * 4 + 2);

    float f[8];
#pragma unroll
    for (int o = 0; o < 8; ++o) f[o] = mf[o * HW + p];

#pragma unroll 2
    for (int j = 0; j < 10; ++j) {
        const float* spj = &sp[j * 169];
        const float rel0 = (float)(sdet[2 * j] * 4) - fx;
        const float rel1 = (float)(sdet[2 * j + 1] * 4) - fy;
        float h0[8];
#pragma unroll
        for (int o = 0; o < 8; ++o) {
            float a = spj[152 + o] + spj[o * 10] * rel0 + spj[o * 10 + 1] * rel1;
#pragma unroll
            for (int c = 0; c < 8; ++c) a += spj[o * 10 + 2 + c] * f[c];
            h0[o] = fmaxf(a, 0.f);
        }
        float h1[8];
#pragma unroll
        for (int o = 0; o < 8; ++o) {
            float a = spj[160 + o];
#pragma unroll
            for (int c = 0; c < 8; ++c) a += spj[80 + o * 8 + c] * h0[c];
            h1[o] = fmaxf(a, 0.f);
        }
        float r = spj[168];
#pragma unroll
        for (int c = 0; c < 8; ++c) r += spj[144 + c] * h1[c];
        out[(kg * 10 + j) * HW + p] = r;
    }
}

// ===========================================================================
extern "C" void kernel_launch(void* const* d_in, const int* in_sizes, int n_in,
                              void* d_out, int out_size, void* d_ws, size_t ws_size,
                              hipStream_t stream)
{
    const float* cnn    = (const float*)d_in[0];
    const float* towerw = (const float*)d_in[1];
    const float* gamma  = (const float*)d_in[2];
    const float* beta   = (const float*)d_in[3];
    const float* meanp  = (const float*)d_in[4];
    const float* varp   = (const float*)d_in[5];
    const float* projw  = (const float*)d_in[6];
    const float* projb  = (const float*)d_in[7];
    const float* ctrlw  = (const float*)d_in[8];
    const float* ctrlb  = (const float*)d_in[9];
    const int*   det    = (const int*)d_in[10];
    float* out = (float*)d_out;

    char*  outb     = (char*)d_out;
    char*  X        = outb;                          // 6,553,600 B
    char*  wbf      = outb + 6553600;                // 1,179,648 B
    float* invshift = (float*)(outb + 7733248);      // 4,096 B
    float* cwT      = (float*)(outb + 7737344);      // 778,752 B (ends 8,516,096)

    char*  Y      = (char*)d_ws;                     // 6,553,600 B
    float* mf     = (float*)((char*)d_ws + 6553600); // 819,200 B
    float* params = (float*)((char*)d_ws + 7372800); // 67,600 B

    fused_prep<<<dim3(1217), dim3(256), 0, stream>>>(
        cnn, towerw, gamma, beta, meanp, varp, ctrlw,
        X, wbf, invshift, cwT);

    // conv1 carries the 100 ctrl blocks (hidden under the conv's runtime)
    conv_mfma<0, 1><<<dim3(300), dim3(512), 0, stream>>>(
        X, wbf + 0 * 294912, invshift + 0 * 256, Y,
        nullptr, nullptr, nullptr,
        cnn, cwT, ctrlb, det, params);
    conv_mfma<0, 0><<<dim3(200), dim3(512), 0, stream>>>(
        Y, wbf + 1 * 294912, invshift + 1 * 256, X,
        nullptr, nullptr, nullptr,
        nullptr, nullptr, nullptr, nullptr, nullptr);
    conv_mfma<0, 0><<<dim3(200), dim3(512), 0, stream>>>(
        X, wbf + 2 * 294912, invshift + 2 * 256, Y,
        nullptr, nullptr, nullptr,
        nullptr, nullptr, nullptr, nullptr, nullptr);
    conv_mfma<1, 0><<<dim3(200), dim3(512), 0, stream>>>(
        Y, wbf + 3 * 294912, invshift + 3 * 256, nullptr,
        projw, projb, mf,
        nullptr, nullptr, nullptr, nullptr, nullptr);

    head_kernel<<<dim3(100, 10), dim3(256), 0, stream>>>(mf, params, det, out);
}

// Round 23
// 102.297 us; speedup vs baseline: 1.1687x; 1.0165x over previous
//
#include <hip/hip_runtime.h>
#include <hip/hip_bf16.h>

#define H 160
#define W 160
#define HW 25600
#define ROWB 40960      // W * 256 bytes per NHWC row

typedef __attribute__((ext_vector_type(8))) short bf16x8;
typedef __attribute__((ext_vector_type(4))) float f32x4;
typedef __attribute__((ext_vector_type(8))) unsigned short ushort8v;
typedef __attribute__((ext_vector_type(4))) unsigned short ushort4v;

typedef __attribute__((address_space(1))) const unsigned int gu32;
typedef __attribute__((address_space(3))) unsigned int lu32;

__device__ __forceinline__ void gload16(const void* g, void* l) {
    __builtin_amdgcn_global_load_lds((gu32*)g, (lu32*)l, 16, 0, 0);
}

__device__ __forceinline__ unsigned short f2b(float f) {
    unsigned int u = __float_as_uint(f);
    unsigned int r = (u + 0x7fffu + ((u >> 16) & 1u)) >> 16;
    return (unsigned short)r;
}
__device__ __forceinline__ float b2f(unsigned short b) {
    return __uint_as_float(((unsigned int)b) << 16);
}

#define LGKM0() asm volatile("s_waitcnt lgkmcnt(0)" ::: "memory")
#define BARRIER() asm volatile("s_barrier" ::: "memory")

// ---------------------------------------------------------------------------
// Activation global format (16-B-slot swizzle, key = p&15):
//   pixel p: 256 B; slot for ci-block cb stored at slot cb^(p&15).
// Weight planes: [l][tap][kk] 8192 B planes of [co][64 B].
// d_out scratch: [0,6553600) act X | [6553600,7733248) wbf |
//   [7733248,7737344) BN inv/shift | [7737344,8516096) cwT (1152x169 f32)
// ws: [0,6553600) act Y | mf 819200 B | params 67600 B   (7,440,400 proven)
// ---------------------------------------------------------------------------

// ===========================================================================
// fused_prep (blockIdx ranges):
//   [0,200)    prep_in — 128 px/block, block-local full-slot coverage (proven)
//   [200,456)  prep_w  — proven coalesced weight transform + BN constants
//   [456,1217) cw transpose: cwT[j*169+o] = cw[o*1152+j]  (coalesced writes)
// ===========================================================================
__global__ __launch_bounds__(256) void fused_prep(
    const float* __restrict__ cnn,
    const float* __restrict__ tw,
    const float* __restrict__ gamma, const float* __restrict__ beta,
    const float* __restrict__ mean,  const float* __restrict__ var,
    const float* __restrict__ cw,
    char* __restrict__ actX, char* __restrict__ wbf,
    float* __restrict__ invshift, float* __restrict__ cwT)
{
    const int tid = threadIdx.x;
    const int b = blockIdx.x;

    if (b < 200) {
        // ---------------- prep_in v4 (proven WRITE_SIZE-clean) -------------
        int blk = b;                            // 0..199
        int p0  = blk * 128 + (tid & 31) * 4;   // 4 consecutive pixels
        int cbh = tid >> 5;                     // 0..7
#pragma unroll
        for (int pass = 0; pass < 2; ++pass) {
            int cb2 = pass * 8 + cbh;
            int ci0 = cb2 * 8;
            ushort8v o0, o1, o2, o3;
#pragma unroll
            for (int jj = 0; jj < 8; ++jj) {
                float4 v = *(const float4*)&cnn[(ci0 + jj) * HW + p0];
                o0[jj] = f2b(v.x);
                o1[jj] = f2b(v.y);
                o2[jj] = f2b(v.z);
                o3[jj] = f2b(v.w);
            }
            *(ushort8v*)(actX + (p0 + 0) * 256 + ((cb2 ^ ((p0 + 0) & 15)) * 16)) = o0;
            *(ushort8v*)(actX + (p0 + 1) * 256 + ((cb2 ^ ((p0 + 1) & 15)) * 16)) = o1;
            *(ushort8v*)(actX + (p0 + 2) * 256 + ((cb2 ^ ((p0 + 2) & 15)) * 16)) = o2;
            *(ushort8v*)(actX + (p0 + 3) * 256 + ((cb2 ^ ((p0 + 3) & 15)) * 16)) = o3;
        }
    } else if (b < 456) {
        // ---------------- prep_weights (proven) ----------------------------
        int idx = (b - 200) * 256 + tid;            // 65,536 exact
        int ci = idx & 127;
        int co = (idx >> 7) & 127;
        int l  = idx >> 14;                          // 0..3
        int kk = ci >> 5;
        int cw2 = ci & 31;
        const float* src = tw + ((l * 128 + co) * 128 + ci) * 9;
        char* dst = wbf + l * 294912 + kk * 8192 + co * 64 + cw2 * 2;
#pragma unroll
        for (int t = 0; t < 9; ++t)
            *(unsigned short*)(dst + t * 32768) = f2b(src[t]);

        if (b == 200) {
            for (int c = tid; c < 512; c += 256) {
                int ll = c >> 7, ch = c & 127;
                float inv = gamma[ll * 128 + ch] * rsqrtf(var[ll * 128 + ch] + 1e-5f);
                float sh  = beta[ll * 128 + ch] - mean[ll * 128 + ch] * inv;
                invshift[ll * 256 + ch] = inv;
                invshift[ll * 256 + 128 + ch] = sh;
            }
        }
    } else {
        // ---------------- cw transpose -------------------------------------
        int idx = (b - 456) * 256 + tid;            // < 194,688
        if (idx < 194688) {
            int j = idx / 169;
            int o = idx - j * 169;
            cwT[idx] = cw[o * 1152 + j];
        }
    }
}

// ===========================================================================
// conv_mfma v9: 18 stages (2 kk per stage) — halves sync-point count.
// Block 512 thr / 8 waves, tile 128co x 128px, 1-D grid b -> (b%10,b/10).
// WQ = 2 halves x 16 KB (planes 2J,2J+1 of stage J in half J&1).
// Stage: vmcnt -> 12 ds_read + 16 MFMA -> barrier -> issue 2-plane DMA.
// ctrl v6 (CTRL=1, blocks >= 200) and epilogues unchanged (validated).
// ===========================================================================
template <int PROJ, int CTRL>
__global__ __launch_bounds__(512, 1) void conv_mfma(
    const char* __restrict__ actin,
    const char* __restrict__ wpl,         // 36 x 8192 B (this layer)
    const float* __restrict__ invshift_l, // 256 f32
    char* __restrict__ actout,            // PROJ=0
    const float* __restrict__ pw,         // PROJ=1: (8,128)
    const float* __restrict__ pb,         // (8)
    float* __restrict__ mf,               // (8,HW)
    const float* __restrict__ cnn,        // CTRL=1
    const float* __restrict__ cwT,        // (1152,169)
    const float* __restrict__ cbp,        // (169)
    const int*   __restrict__ det,        // (100,2)
    float* __restrict__ params)           // (100,169)
{
    __shared__ __align__(16) char smem[78848];

    const int tid  = threadIdx.x;

    if (CTRL && blockIdx.x >= 200) {
        // ---------------- ctrl v6: 3 K-chunks x 169 outputs (proven) -------
        float* patch = (float*)smem;            // 1152 f32
        float* sred  = (float*)(smem + 4608);   // 338 f32
        const int k = blockIdx.x - 200;
        const int xk = det[2 * k];
        const int yk = det[2 * k + 1];
        for (int i = tid; i < 1152; i += 512) {
            int ci = i / 9;
            int rem = i - ci * 9;
            int r = rem / 3, s = rem - r * 3;
            int gy = yk + r - 1, gx = xk + s - 1;
            float v = 0.f;
            if ((unsigned)gy < (unsigned)H && (unsigned)gx < (unsigned)W)
                v = cnn[ci * HW + gy * W + gx];
            patch[i] = v;
        }
        __syncthreads();

        float acc = 0.f;
        if (tid < 507) {
            const int chunk = tid / 169;        // 0..2
            const int o = tid - chunk * 169;
            const int j0 = chunk * 384;
            const float* cp = cwT + o;
#pragma unroll 8
            for (int j = j0; j < j0 + 384; ++j)
                acc += cp[j * 169] * patch[j];
        }
        if (tid >= 169 && tid < 507) sred[tid - 169] = acc;
        __syncthreads();
        if (tid < 169)
            params[k * 169 + tid] = acc + sred[tid] + sred[169 + tid] + cbp[tid];
        return;
    }

    char* IT = smem;                 // 46080 B : [10 rows][18 px][256 B]
    char* WQ = smem + 46080;         // 2 x 16384 B half-buffers

    const int lane = tid & 63;
    const int w    = tid >> 6;       // 0..7
    const int wp   = w >> 1;         // 0..3 : rows wp*2, wp*2+1
    const int wc   = w & 1;          // co half (64 co)
    const int g    = lane >> 4;
    const int i15  = lane & 15;

    const int bb = blockIdx.x;
    const int bx = bb % 10;          // 0..9
    const int by = bb / 10;          // 0..19
    const int tx0 = bx * 16 - 1;
    const int ty0 = by * 8 - 1;

    // ---- prologue: input tile DMA (clamped) + weight planes 0..3
    for (int it = 0; it < 6; ++it) {
        int c = it * 512 + tid;
        if (c < 2880) {                       // 2880 % 64 == 0: whole waves
            int row  = c / 288;
            int rem  = c - row * 288;
            int px_i = rem >> 4;
            int bo   = (rem & 15) * 16;
            int cy = min(max(ty0 + row, 0), H - 1);
            int cx = min(max(tx0 + px_i, 0), W - 1);
            char* ldsb = IT + (it * 512 + (tid & ~63)) * 16;
            gload16(actin + cy * ROWB + cx * 256 + bo, ldsb);
        }
    }
#pragma unroll
    for (int pl = 0; pl < 4; ++pl)
        gload16(wpl + pl * 8192 + tid * 16,
                WQ + pl * 8192 + (tid & ~63) * 16);
    asm volatile("s_waitcnt vmcnt(4)" ::: "memory");   // IT landed
    for (int c = tid; c < 2880; c += 512) {            // zero own OOB chunks
        int row  = c / 288;
        int rem  = c - row * 288;
        int px_i = rem >> 4;
        int gy = ty0 + row, gx = tx0 + px_i;
        if ((unsigned)gy >= (unsigned)H || (unsigned)gx >= (unsigned)W) {
            f32x4 z = {0.f, 0.f, 0.f, 0.f};
            *(f32x4*)(IT + c * 16) = z;
        }
    }
    LGKM0();
    BARRIER();

    f32x4 acc[4][2];                 // [cf][pf] — compile-time indices only
#pragma unroll
    for (int cf = 0; cf < 4; ++cf)
#pragma unroll
        for (int pf = 0; pf < 2; ++pf)
            acc[cf][pf] = (f32x4){0.f, 0.f, 0.f, 0.f};

// one kk half-step: 4 A-frag + 2 B-frag ds_reads, 8 MFMA
#define KKHALF(J, KKQ) {                                                       \
    const int tap = (J) >> 1;                                                  \
    const int r = tap / 3, s = tap - r * 3;                                    \
    const int kk = (((J) & 1) << 1) + (KKQ);                                   \
    const char* wbse = WQ + ((J) & 1) * 16384 + (KKQ) * 8192                   \
                       + (wc * 64 + i15) * 64 + g * 16;                        \
    bf16x8 a0 = *(const bf16x8*)(wbse + 0 * 1024);                             \
    bf16x8 a1 = *(const bf16x8*)(wbse + 1 * 1024);                             \
    bf16x8 a2 = *(const bf16x8*)(wbse + 2 * 1024);                             \
    bf16x8 a3 = *(const bf16x8*)(wbse + 3 * 1024);                             \
    const int slotb = ((kk * 4 + g) ^ ((i15 + s + 15) & 15)) * 16;             \
    const char* ib = IT + (i15 + s) * 256 + slotb;                             \
    bf16x8 b0 = *(const bf16x8*)(ib + (wp * 2 + 0 + r) * 4608);                \
    bf16x8 b1 = *(const bf16x8*)(ib + (wp * 2 + 1 + r) * 4608);                \
    acc[0][0] = __builtin_amdgcn_mfma_f32_16x16x32_bf16(a0, b0, acc[0][0], 0, 0, 0); \
    acc[0][1] = __builtin_amdgcn_mfma_f32_16x16x32_bf16(a0, b1, acc[0][1], 0, 0, 0); \
    acc[1][0] = __builtin_amdgcn_mfma_f32_16x16x32_bf16(a1, b0, acc[1][0], 0, 0, 0); \
    acc[1][1] = __builtin_amdgcn_mfma_f32_16x16x32_bf16(a1, b1, acc[1][1], 0, 0, 0); \
    acc[2][0] = __builtin_amdgcn_mfma_f32_16x16x32_bf16(a2, b0, acc[2][0], 0, 0, 0); \
    acc[2][1] = __builtin_amdgcn_mfma_f32_16x16x32_bf16(a2, b1, acc[2][1], 0, 0, 0); \
    acc[3][0] = __builtin_amdgcn_mfma_f32_16x16x32_bf16(a3, b0, acc[3][0], 0, 0, 0); \
    acc[3][1] = __builtin_amdgcn_mfma_f32_16x16x32_bf16(a3, b1, acc[3][1], 0, 0, 0); \
}

// stage J: wait pair J -> compute 2 kk -> barrier -> issue pair J+2
#define CSTAGE2(J, WN) {                                                       \
    asm volatile("s_waitcnt vmcnt(" #WN ")" ::: "memory");                     \
    KKHALF(J, 0)                                                               \
    KKHALF(J, 1)                                                               \
    BARRIER();                                                                 \
    if ((J) <= 15) {                                                           \
        const char* src = wpl + ((J) * 2 + 4) * 8192;                          \
        char* dst = WQ + ((J) & 1) * 16384;                                    \
        gload16(src + tid * 16,        dst + (tid & ~63) * 16);                \
        gload16(src + 8192 + tid * 16, dst + 8192 + (tid & ~63) * 16);         \
    }                                                                          \
}

    CSTAGE2(0,2)  CSTAGE2(1,2)  CSTAGE2(2,2)  CSTAGE2(3,2)  CSTAGE2(4,2)
    CSTAGE2(5,2)  CSTAGE2(6,2)  CSTAGE2(7,2)  CSTAGE2(8,2)  CSTAGE2(9,2)
    CSTAGE2(10,2) CSTAGE2(11,2) CSTAGE2(12,2) CSTAGE2(13,2) CSTAGE2(14,2)
    CSTAGE2(15,2) CSTAGE2(16,2) CSTAGE2(17,0)
#undef CSTAGE2
#undef KKHALF

    // ---- epilogue ---------------------------------------------------------
    if (PROJ == 0) {
        const int gx = bx * 16 + i15;    // gx & 15 == i15
#pragma unroll
        for (int cf = 0; cf < 4; ++cf) {
            int co0 = wc * 64 + cf * 16 + g * 4;
            int cbx = wc * 8 + cf * 2 + (g >> 1);
            int sbyte = ((cbx ^ i15) * 16) + (g & 1) * 8;
            f32x4 inv4 = *(const f32x4*)&invshift_l[co0];
            f32x4 sh4  = *(const f32x4*)&invshift_l[128 + co0];
#pragma unroll
            for (int pf = 0; pf < 2; ++pf) {
                int gy = by * 8 + wp * 2 + pf;
                f32x4 v = acc[cf][pf];
                ushort4v o;
                o.x = f2b(fmaxf(v.x * inv4.x + sh4.x, 0.f));
                o.y = f2b(fmaxf(v.y * inv4.y + sh4.y, 0.f));
                o.z = f2b(fmaxf(v.z * inv4.z + sh4.z, 0.f));
                o.w = f2b(fmaxf(v.w * inv4.w + sh4.w, 0.f));
                *(ushort4v*)(actout + gy * ROWB + gx * 256 + sbyte) = o;
            }
        }
    } else {
        // fused projection: BN'd layer-4 acts -> actF in LDS, then 8-ch proj
        char* actF = smem;                       // 32 KB [128px][256B]
        float* spw = (float*)(smem + 32768);     // 4 KB
        __syncthreads();                         // everyone done with IT/WQ
#pragma unroll
        for (int cf = 0; cf < 4; ++cf) {
            int co0 = wc * 64 + cf * 16 + g * 4;
            int cbx = wc * 8 + cf * 2 + (g >> 1);
            int sbyte = ((cbx ^ i15) * 16) + (g & 1) * 8;
            f32x4 inv4 = *(const f32x4*)&invshift_l[co0];
            f32x4 sh4  = *(const f32x4*)&invshift_l[128 + co0];
#pragma unroll
            for (int pf = 0; pf < 2; ++pf) {
                int px = (wp * 2 + pf) * 16 + i15;   // px & 15 == i15
                f32x4 v = acc[cf][pf];
                ushort4v o;
                o.x = f2b(fmaxf(v.x * inv4.x + sh4.x, 0.f));
                o.y = f2b(fmaxf(v.y * inv4.y + sh4.y, 0.f));
                o.z = f2b(fmaxf(v.z * inv4.z + sh4.z, 0.f));
                o.w = f2b(fmaxf(v.w * inv4.w + sh4.w, 0.f));
                *(ushort4v*)(actF + px * 256 + sbyte) = o;
            }
        }
        for (int i = tid; i < 1024; i += 512) spw[i] = pw[i];
        __syncthreads();
        int pxt = tid >> 2;            // 0..127
        int o0  = (tid & 3) * 2;       // 0,2,4,6
        float s0 = 0.f, s1 = 0.f;
#pragma unroll
        for (int cb2 = 0; cb2 < 16; ++cb2) {
            ushort8v vv = *(const ushort8v*)(actF + pxt * 256 + ((cb2 ^ (pxt & 15)) * 16));
#pragma unroll
            for (int j = 0; j < 8; ++j) {
                float f = b2f(vv[j]);
                int ci = cb2 * 8 + j;
                s0 += f * spw[o0 * 128 + ci];
                s1 += f * spw[(o0 + 1) * 128 + ci];
            }
        }
        int p = (by * 8 + (pxt >> 4)) * W + bx * 16 + (pxt & 15);
        mf[o0 * HW + p]       = s0 + pb[o0];
        mf[(o0 + 1) * HW + p] = s1 + pb[o0 + 1];
    }
}

// ===========================================================================
// head: 10 detections per block; mf read once, reused 10x (proven).
// ===========================================================================
__global__ __launch_bounds__(256) void head_kernel(
    const float* __restrict__ mf, const float* __restrict__ params,
    const int* __restrict__ det, float* __restrict__ out)
{
    __shared__ float sp[1690];
    __shared__ int sdet[20];
    const int tid = threadIdx.x;
    const int kg = blockIdx.y;
    for (int i = tid; i < 1690; i += 256) sp[i] = params[kg * 1690 + i];
    if (tid < 20) sdet[tid] = det[kg * 20 + tid];
    __syncthreads();

    const int p = blockIdx.x * 256 + tid;
    const int x = p % W;
    const int y = p / W;
    const float fx = (float)(x * 4 + 2);
    const float fy = (float)(y * 4 + 2);

    float f[8];
#pragma unroll
    for (int o = 0; o < 8; ++o) f[o] = mf[o * HW + p];

#pragma unroll 2
    for (int j = 0; j < 10; ++j) {
        const float* spj = &sp[j * 169];
        const float rel0 = (float)(sdet[2 * j] * 4) - fx;
        const float rel1 = (float)(sdet[2 * j + 1] * 4) - fy;
        float h0[8];
#pragma unroll
        for (int o = 0; o < 8; ++o) {
            float a = spj[152 + o] + spj[o * 10] * rel0 + spj[o * 10 + 1] * rel1;
#pragma unroll
            for (int c = 0; c < 8; ++c) a += spj[o * 10 + 2 + c] * f[c];
            h0[o] = fmaxf(a, 0.f);
        }
        float h1[8];
#pragma unroll
        for (int o = 0; o < 8; ++o) {
            float a = spj[160 + o];
#pragma unroll
            for (int c = 0; c < 8; ++c) a += spj[80 + o * 8 + c] * h0[c];
            h1[o] = fmaxf(a, 0.f);
        }
        float r = spj[168];
#pragma unroll
        for (int c = 0; c < 8; ++c) r += spj[144 + c] * h1[c];
        out[(kg * 10 + j) * HW + p] = r;
    }
}

// ===========================================================================
extern "C" void kernel_launch(void* const* d_in, const int* in_sizes, int n_in,
                              void* d_out, int out_size, void* d_ws, size_t ws_size,
                              hipStream_t stream)
{
    const float* cnn    = (const float*)d_in[0];
    const float* towerw = (const float*)d_in[1];
    const float* gamma  = (const float*)d_in[2];
    const float* beta   = (const float*)d_in[3];
    const float* meanp  = (const float*)d_in[4];
    const float* varp   = (const float*)d_in[5];
    const float* projw  = (const float*)d_in[6];
    const float* projb  = (const float*)d_in[7];
    const float* ctrlw  = (const float*)d_in[8];
    const float* ctrlb  = (const float*)d_in[9];
    const int*   det    = (const int*)d_in[10];
    float* out = (float*)d_out;

    char*  outb     = (char*)d_out;
    char*  X        = outb;                          // 6,553,600 B
    char*  wbf      = outb + 6553600;                // 1,179,648 B
    float* invshift = (float*)(outb + 7733248);      // 4,096 B
    float* cwT      = (float*)(outb + 7737344);      // 778,752 B (ends 8,516,096)

    char*  Y      = (char*)d_ws;                     // 6,553,600 B
    float* mf     = (float*)((char*)d_ws + 6553600); // 819,200 B
    float* params = (float*)((char*)d_ws + 7372800); // 67,600 B

    fused_prep<<<dim3(1217), dim3(256), 0, stream>>>(
        cnn, towerw, gamma, beta, meanp, varp, ctrlw,
        X, wbf, invshift, cwT);

    // conv1 carries the 100 ctrl blocks (hidden under the conv's runtime)
    conv_mfma<0, 1><<<dim3(300), dim3(512), 0, stream>>>(
        X, wbf + 0 * 294912, invshift + 0 * 256, Y,
        nullptr, nullptr, nullptr,
        cnn, cwT, ctrlb, det, params);
    conv_mfma<0, 0><<<dim3(200), dim3(512), 0, stream>>>(
        Y, wbf + 1 * 294912, invshift + 1 * 256, X,
        nullptr, nullptr, nullptr,
        nullptr, nullptr, nullptr, nullptr, nullptr);
    conv_mfma<0, 0><<<dim3(200), dim3(512), 0, stream>>>(
        X, wbf + 2 * 294912, invshift + 2 * 256, Y,
        nullptr, nullptr, nullptr,
        nullptr, nullptr, nullptr, nullptr, nullptr);
    conv_mfma<1, 0><<<dim3(200), dim3(512), 0, stream>>>(
        Y, wbf + 3 * 294912, invshift + 3 * 256, nullptr,
        projw, projb, mf,
        nullptr, nullptr, nullptr, nullptr, nullptr);

    head_kernel<<<dim3(100, 10), dim3(256), 0, stream>>>(mf, params, det, out);
}